// Round 4
// baseline (576.075 us; speedup 1.0000x reference)
//
#include <hip/hip_runtime.h>
#include <cstdint>

#define S_LEN 2048
#define HID   4096
#define NHQ   32
#define NKV   8
#define HD    128
#define QKV_N 6144

typedef float  f32x4 __attribute__((ext_vector_type(4)));
typedef short  s16x8 __attribute__((ext_vector_type(8)));
typedef unsigned short ushort_t;

typedef __attribute__((address_space(3))) void       lds_void;
typedef const __attribute__((address_space(1))) void gbl_void;

__device__ __forceinline__ void gload_lds16(const void* g, void* l) {
  __builtin_amdgcn_global_load_lds((gbl_void*)g, (lds_void*)l, 16, 0, 0);
}

__device__ __forceinline__ short f2bf_bits(float f) {
  union { __bf16 b; short s; } u;
  u.b = (__bf16)f;
  return u.s;
}
__device__ __forceinline__ float bf2f(unsigned short u) {
  union { unsigned int i; float f; } x;
  x.i = ((unsigned int)u) << 16;
  return x.f;
}

__device__ __forceinline__ void cvt8(const float* src, ushort_t* dst, int j) {
  const f32x4* s = (const f32x4*)src;
  f32x4 a = s[j * 2], b = s[j * 2 + 1];
  s16x8 r;
  r[0] = f2bf_bits(a[0]); r[1] = f2bf_bits(a[1]); r[2] = f2bf_bits(a[2]); r[3] = f2bf_bits(a[3]);
  r[4] = f2bf_bits(b[0]); r[5] = f2bf_bits(b[1]); r[6] = f2bf_bits(b[2]); r[7] = f2bf_bits(b[3]);
  *((s16x8*)dst + j) = r;
}

// ---------------- fused cvt: hidden (1048576 vec8) + w_qkv (3145728 vec8) ----------------
__global__ __launch_bounds__(256)
void cvt_hw(const float* __restrict__ h, const float* __restrict__ wq,
            ushort_t* __restrict__ hb, ushort_t* __restrict__ wqb) {
  int i = blockIdx.x * 256 + threadIdx.x;
  if (i < 1048576) cvt8(h, hb, i);
  else             cvt8(wq, wqb, i - 1048576);
}

// ---------------- counted-vmcnt waits ----------------
template <int N> __device__ __forceinline__ void wait_vm() {
  if constexpr (N == 6)      asm volatile("s_waitcnt vmcnt(6)" ::: "memory");
  else if constexpr (N == 4) asm volatile("s_waitcnt vmcnt(4)" ::: "memory");
  else                       asm volatile("s_waitcnt vmcnt(0)" ::: "memory");
}

// ---------------- 8-phase 256x256 bf16 GEMM, m201 phase ORDERING, C = A * B^T --------
// 512 thr = 8 waves (2M x 4N), per-wave out 128x64 (2 row-halves x 2 col-halves).
// Snake quadrant order per tile: (qm,qn) = (0,0),(0,1),(1,1),(1,0).
// Operand caching (24 ds_read_b128/K-tile/wave, the minimum):
//   ph1: RD A0(8) + B0(4); ph2: RD B1(4); ph3: RD A1(8); ph4: none (all cached).
// Phase body (m201): {ds_read; stage 1 half (2 gload_lds); s_barrier; lgkmcnt(0);
//   sched_barrier(0); setprio(1); 16 MFMA; setprio(0); [vmcnt @ph4/ph8]; s_barrier}.
// Reads issue BEFORE the barrier -> LDS latency overlaps barrier-sync + other waves'
// MFMA (per-wave lgkm stagger = the role-split setprio arbitrates).
// Stage slots (steady, iter i: t0=2i in b0, t1=2i+1 in b1, t0n=2i+2, t1n=2i+3):
//   ph1:A1(t1)->b1   ph2:A0(t0n)->b0  ph3:B0(t0n)->b0  ph4:B1(t0n)->b0  [vmcnt(6)]
//   ph5:A1(t0n)->b0  ph6:A0(t1n)->b1  ph7:B0(t1n)->b1  ph8:B1(t1n)->b1  [vmcnt(6)]
// WAR: every stage >=1 barrier after its region's last ds_read; stage regions disjoint
// from same-phase reads. RAW: vmcnt(6)@ph4 retires prev-ph6..ph8 + ph1 (b1 complete
// before ph5 reads); vmcnt(6)@ph8 retires ph2..ph5 (b0' complete before next ph1).
// Prologue: 7 stages (b0 full + b1 A0,B0,B1), vmcnt(6) retires b0, barrier.
// Epilogue iter: only ph1 stage; ph4 drains vmcnt(0).
template <bool OUTF32>
__global__ __launch_bounds__(512, 2)
void gemm8p(const ushort_t* __restrict__ Ag, const ushort_t* __restrict__ Bg,
            void* __restrict__ Cp, int M, int N, int K) {
  __shared__ __align__(16) ushort_t As[2][2][256 * 32];  // [buf][ksub] 64 KB
  __shared__ __align__(16) ushort_t Bs[2][2][256 * 32];  // 64 KB

  const int t = threadIdx.x;
  const int w = t >> 6, l = t & 63;
  const int n16 = l & 15, quad = l >> 4;
  const int wm = w >> 2, wn = w & 3;
  const int sw16 = (quad ^ (n16 & 3)) * 16;
  const int m0 = blockIdx.x * 256, n0 = blockIdx.y * 256;

  // staging: thread t covers row h*128+(t>>2), chunk t&3, swizzled kseg (t&3)^(row&3);
  // LDS dest linear (base + t*16) as global_load_lds requires.
  const int srow = t >> 2;
  const int schunk = (t & 3) ^ (srow & 3);
  const ushort_t* Abase = Ag + (size_t)(m0 + srow) * K + schunk * 8;
  const ushort_t* Bbase = Bg + (size_t)(n0 + srow) * K + schunk * 8;
  char* AsB = (char*)&As[0][0][0];
  char* BsB = (char*)&Bs[0][0][0];
  const size_t hstep = (size_t)128 * K;

  auto stageA = [&](int b, int h, int tile) {
    const ushort_t* g = Abase + (size_t)h * hstep + tile * 64;
    gload_lds16(g,      AsB + b * 32768 + h * 8192 + t * 16);
    gload_lds16(g + 32, AsB + b * 32768 + 16384 + h * 8192 + t * 16);
  };
  auto stageB = [&](int b, int h, int tile) {
    const ushort_t* g = Bbase + (size_t)h * hstep + tile * 64;
    gload_lds16(g,      BsB + b * 32768 + h * 8192 + t * 16);
    gload_lds16(g + 32, BsB + b * 32768 + 16384 + h * 8192 + t * 16);
  };

  const int aRowBase = wm * 64 + n16;
  const int bRowBase = wn * 32 + n16;

  f32x4 acc[8][4] = {};
  s16x8 af[4][2], bf0[2][2], bf1[2][2];

#define RD_A(b, qm) do {                                                        \
    _Pragma("unroll")                                                           \
    for (int mf = 0; mf < 4; mf++)                                              \
      _Pragma("unroll")                                                         \
      for (int ks = 0; ks < 2; ks++)                                            \
        af[mf][ks] = *(const s16x8*)(AsB + (b) * 32768 + ks * 16384 +           \
                      ((qm) * 128 + mf * 16 + aRowBase) * 64 + sw16);           \
  } while (0)

#define RD_B(b, qn, dst) do {                                                   \
    _Pragma("unroll")                                                           \
    for (int nf = 0; nf < 2; nf++)                                              \
      _Pragma("unroll")                                                         \
      for (int ks = 0; ks < 2; ks++)                                            \
        dst[nf][ks] = *(const s16x8*)(BsB + (b) * 32768 + ks * 16384 +          \
                      ((qn) * 128 + nf * 16 + bRowBase) * 64 + sw16);           \
  } while (0)

#define PHASE(RDS, STG, qm, qn, BFX, VMW) do {                                  \
    RDS;                                                                        \
    STG;                                                                        \
    __builtin_amdgcn_s_barrier();                                               \
    asm volatile("s_waitcnt lgkmcnt(0)" ::: "memory");                          \
    __builtin_amdgcn_sched_barrier(0);                                          \
    __builtin_amdgcn_s_setprio(1);                                              \
    _Pragma("unroll")                                                           \
    for (int ks = 0; ks < 2; ks++)                                              \
      _Pragma("unroll")                                                         \
      for (int mf = 0; mf < 4; mf++)                                            \
        _Pragma("unroll")                                                       \
        for (int nf = 0; nf < 2; nf++)                                          \
          acc[(qm) * 4 + mf][(qn) * 2 + nf] =                                   \
            __builtin_amdgcn_mfma_f32_16x16x32_bf16(af[mf][ks], BFX[nf][ks],    \
                acc[(qm) * 4 + mf][(qn) * 2 + nf], 0, 0, 0);                    \
    __builtin_amdgcn_s_setprio(0);                                              \
    VMW;                                                                        \
    __builtin_amdgcn_s_barrier();                                               \
    asm volatile("" ::: "memory");                                              \
  } while (0)

  const int NT = K >> 6;   // K-tiles (64 for K=4096)
  const int NI = NT >> 1;  // iterations (32)

  // Prologue: b0 full (tile 0) + b1 A0,B0,B1 (tile 1) = 7 stages; retire b0's 4.
  stageA(0, 0, 0); stageB(0, 0, 0); stageB(0, 1, 0); stageA(0, 1, 0);
  stageA(1, 0, 1); stageB(1, 0, 1); stageB(1, 1, 1);
  wait_vm<6>();
  asm volatile("" ::: "memory");
  __builtin_amdgcn_s_barrier();
  asm volatile("" ::: "memory");

  for (int i = 0; i < NI - 1; i++) {
    const int t1 = 2 * i + 1, t0n = 2 * i + 2, t1n = 2 * i + 3;
    PHASE(RD_A(0, 0); RD_B(0, 0, bf0), stageA(1, 1, t1),  0, 0, bf0, ((void)0));
    PHASE(RD_B(0, 1, bf1),             stageA(0, 0, t0n), 0, 1, bf1, ((void)0));
    PHASE(RD_A(0, 1),                  stageB(0, 0, t0n), 1, 1, bf1, ((void)0));
    PHASE(((void)0),                   stageB(0, 1, t0n), 1, 0, bf0, wait_vm<6>());
    PHASE(RD_A(1, 0); RD_B(1, 0, bf0), stageA(0, 1, t0n), 0, 0, bf0, ((void)0));
    PHASE(RD_B(1, 1, bf1),             stageA(1, 0, t1n), 0, 1, bf1, ((void)0));
    PHASE(RD_A(1, 1),                  stageB(1, 0, t1n), 1, 1, bf1, ((void)0));
    PHASE(((void)0),                   stageB(1, 1, t1n), 1, 0, bf0, wait_vm<6>());
  }
  // Epilogue iteration (tiles NT-2 in b0, NT-1 in b1): only ph1's stage remains.
  PHASE(RD_A(0, 0); RD_B(0, 0, bf0), stageA(1, 1, NT - 1), 0, 0, bf0, ((void)0));
  PHASE(RD_B(0, 1, bf1),             ((void)0),            0, 1, bf1, ((void)0));
  PHASE(RD_A(0, 1),                  ((void)0),            1, 1, bf1, ((void)0));
  PHASE(((void)0),                   ((void)0),            1, 0, bf0, wait_vm<0>());
  PHASE(RD_A(1, 0); RD_B(1, 0, bf0), ((void)0),            0, 0, bf0, ((void)0));
  PHASE(RD_B(1, 1, bf1),             ((void)0),            0, 1, bf1, ((void)0));
  PHASE(RD_A(1, 1),                  ((void)0),            1, 1, bf1, ((void)0));
  PHASE(((void)0),                   ((void)0),            1, 0, bf0, ((void)0));
#undef PHASE
#undef RD_A
#undef RD_B

#pragma unroll
  for (int a = 0; a < 8; a++)
#pragma unroll
    for (int bq = 0; bq < 4; bq++)
#pragma unroll
      for (int r = 0; r < 4; r++) {
        int row = m0 + (a >> 2) * 128 + wm * 64 + (a & 3) * 16 + quad * 4 + r;
        int col = n0 + (bq >> 1) * 128 + wn * 32 + (bq & 1) * 16 + n16;
        float v = acc[a][bq][r];
        if constexpr (OUTF32) ((float*)Cp)[(size_t)row * N + col] = v;
        else ((ushort_t*)Cp)[(size_t)row * N + col] = (ushort_t)f2bf_bits(v);
      }
}

// ---------------- fused mid-pipeline: RoPE scatter + V-transpose + cvt(w_o) ----------------
// blocks [0,2048): rope row s; [2048,2560): v_transpose; [2560,10752): w_o cvt.
__global__ __launch_bounds__(256)
void rope_vt_cvtwo(const ushort_t* __restrict__ qkv, ushort_t* __restrict__ Q,
                   ushort_t* __restrict__ Kc, ushort_t* __restrict__ Vt,
                   const float* __restrict__ wo, ushort_t* __restrict__ wob) {
  __shared__ __align__(16) ushort_t tile[64][72];
  const int b = blockIdx.x;
  const int t = threadIdx.x;
  if (b < 2048) {
    const int s = b;
    const float LN1E4_64 = 0.14391156831212787f;  // ln(10000)/64
    for (int item = t; item < (NHQ + NKV) * 64; item += 256) {
      int head = item >> 6, i = item & 63;
      float f = expf(-(float)i * LN1E4_64);
      float ang = (float)s * f;
      float sn, cs;
      sincosf(ang, &sn, &cs);
      if (head < NHQ) {
        const ushort_t* src = qkv + (size_t)s * QKV_N + head * HD;
        float x1 = bf2f(src[i]), x2 = bf2f(src[64 + i]);
        const float sc = 0.08838834764831845f;  // 1/sqrt(128)
        ushort_t* dst = Q + ((size_t)head * S_LEN + s) * HD;
        dst[i]      = (ushort_t)f2bf_bits((x1 * cs - x2 * sn) * sc);
        dst[64 + i] = (ushort_t)f2bf_bits((x1 * sn + x2 * cs) * sc);
      } else {
        int kv = head - NHQ;
        const ushort_t* src = qkv + (size_t)s * QKV_N + 4096 + kv * HD;
        float x1 = bf2f(src[i]), x2 = bf2f(src[64 + i]);
        ushort_t* dst = Kc + ((size_t)kv * S_LEN + s) * HD;
        dst[i]      = (ushort_t)f2bf_bits(x1 * cs - x2 * sn);
        dst[64 + i] = (ushort_t)f2bf_bits(x1 * sn + x2 * cs);
      }
    }
  } else if (b < 2560) {
    const int bb = b - 2048;
    const int s0 = (bb & 31) * 64;
    const int by = bb >> 5;
    const int kv = by >> 1;
    const int d0 = (by & 1) * 64;
    {
      int r = t >> 2, c = (t & 3) * 16;
      const ushort_t* src = qkv + (size_t)(s0 + r) * QKV_N + 5120 + kv * HD + d0 + c;
      *(s16x8*)&tile[r][c]     = *(const s16x8*)src;
      *(s16x8*)&tile[r][c + 8] = *(const s16x8*)(src + 8);
    }
    __syncthreads();
    {
      int d = t >> 2, sseg = (t & 3) * 16;
      ushort_t* dst = Vt + ((size_t)kv * HD + d0 + d) * S_LEN + s0 + sseg;
      s16x8 o1, o2;
#pragma unroll
      for (int i = 0; i < 8; i++) { o1[i] = tile[sseg + i][d]; o2[i] = tile[sseg + 8 + i][d]; }
      *(s16x8*)dst = o1;
      *(s16x8*)(dst + 8) = o2;
    }
  } else {
    int j = (b - 2560) * 256 + t;  // 2097152 vec8 of w_o
    cvt8(wo, wob, j);
  }
}

// ---------------- Flash attention (unchanged) ----------------
__global__ __launch_bounds__(256)
void attn_kernel(const ushort_t* __restrict__ Q, const ushort_t* __restrict__ Kc,
                 const ushort_t* __restrict__ Vt, ushort_t* __restrict__ Out) {
  __shared__ __align__(16) ushort_t Ks[2][64 * 128];   // 32 KB
  __shared__ __align__(16) ushort_t Vs[2][128 * 64];   // 32 KB
  __shared__ __align__(16) ushort_t Pl[4][16 * 72];    // 9 KB
  const int bx = blockIdx.x;                            // 0..15
  const int h = blockIdx.y;
  const int t = threadIdx.x, w = t >> 6, l = t & 63;
  const int n16 = l & 15, quad = l >> 4;
  const int kv = h >> 2;
  const ushort_t* Qh = Q  + (size_t)h  * S_LEN * HD;
  const ushort_t* Kh = Kc + (size_t)kv * S_LEN * HD;
  const ushort_t* Vh = Vt + (size_t)kv * HD * S_LEN;

  const int qtA = bx, qtB = 31 - bx;
  const int q0A = qtA * 64 + w * 16, q0B = qtB * 64 + w * 16;
  const int tripsA = qtA + 1;
  const int TOTAL = 33;

  s16x8 qfA[4], qfB[4];
#pragma unroll
  for (int ks = 0; ks < 4; ks++) {
    qfA[ks] = *(const s16x8*)(Qh + (size_t)(q0A + n16) * HD + ks * 32 + quad * 8);
    qfB[ks] = *(const s16x8*)(Qh + (size_t)(q0B + n16) * HD + ks * 32 + quad * 8);
  }

  s16x8 ones;
  {
    short v = (n16 == 0) ? (short)0x3F80 : (short)0;
#pragma unroll
    for (int j = 0; j < 8; j++) ones[j] = v;
  }

  f32x4 o[9] = {};
  float mrun[4] = {-1e30f, -1e30f, -1e30f, -1e30f};

  ushort_t* P = Pl[w];

  auto stage = [&](int k0, int buf) {
#pragma unroll
    for (int c = 0; c < 4; c++) {
      int idx = (c * 4 + w) * 64 + l;
      int row = idx >> 4, sc = idx & 15;
      int dseg = sc ^ (row & 15);
      gload_lds16(Kh + (size_t)(k0 + row) * HD + dseg * 8,
                  (char*)&Ks[buf][0] + (c * 4 + w) * 1024);
    }
#pragma unroll
    for (int c = 0; c < 4; c++) {
      int idx = (c * 4 + w) * 64 + l;
      int row = idx >> 3, sc = idx & 7;
      int ks2 = sc ^ (row & 7);
      gload_lds16(Vh + (size_t)row * S_LEN + k0 + ks2 * 8,
                  (char*)&Vs[buf][0] + (c * 4 + w) * 1024);
    }
  };

  stage(0, 0);

  for (int i = 0; i < TOTAL; i++) {
    const bool isA = (i < tripsA);
    const int kt = isA ? i : i - tripsA;
    const int q0 = isA ? q0A : q0B;
    const int k0 = kt * 64;
    const int buf = i & 1;

    __syncthreads();

    if (i + 1 < TOTAL) {
      const bool nA = (i + 1 < tripsA);
      const int nkt = nA ? (i + 1) : (i + 1 - tripsA);
      stage(nkt * 64, buf ^ 1);
    }

    const ushort_t* KsB = &Ks[buf][0];
    const ushort_t* VsB = &Vs[buf][0];

    f32x4 sacc[4] = {};
#pragma unroll
    for (int ks = 0; ks < 4; ks++) {
      s16x8 qf = isA ? qfA[ks] : qfB[ks];
#pragma unroll
      for (int nt = 0; nt < 4; nt++) {
        int row = nt * 16 + n16;
        s16x8 kf = *(const s16x8*)(KsB + row * 128 + ((ks * 4 + quad) ^ (row & 15)) * 8);
        sacc[nt] = __builtin_amdgcn_mfma_f32_16x16x32_bf16(qf, kf, sacc[nt], 0, 0, 0);
      }
    }

    if (k0 + 63 > q0) {
#pragma unroll
      for (int nt = 0; nt < 4; nt++)
#pragma unroll
        for (int r = 0; r < 4; r++) {
          int qrow = q0 + quad * 4 + r;
          int key  = k0 + nt * 16 + n16;
          if (key > qrow) sacc[nt][r] = -1e30f;
        }
    }

#pragma unroll
    for (int r = 0; r < 4; r++) {
      float tmx = fmaxf(fmaxf(sacc[0][r], sacc[1][r]), fmaxf(sacc[2][r], sacc[3][r]));
#pragma unroll
      for (int d = 1; d < 16; d <<= 1) tmx = fmaxf(tmx, __shfl_xor(tmx, d));
      float nm = fmaxf(mrun[r], tmx);
      float alpha = __expf(mrun[r] - nm);
      mrun[r] = nm;
#pragma unroll
      for (int nt = 0; nt < 4; nt++) sacc[nt][r] = __expf(sacc[nt][r] - nm);
#pragma unroll
      for (int nt2 = 0; nt2 < 9; nt2++) o[nt2][r] *= alpha;
    }

#pragma unroll
    for (int nt = 0; nt < 4; nt++)
#pragma unroll
      for (int r = 0; r < 4; r++)
        P[(quad * 4 + r) * 72 + nt * 16 + n16] = (ushort_t)f2bf_bits(sacc[nt][r]);
    asm volatile("s_waitcnt lgkmcnt(0)" ::: "memory");
    s16x8 pa[2];
#pragma unroll
    for (int kseg = 0; kseg < 2; kseg++)
      pa[kseg] = *(const s16x8*)(P + n16 * 72 + kseg * 32 + quad * 8);

#pragma unroll
    for (int kseg = 0; kseg < 2; kseg++) {
#pragma unroll
      for (int ntd = 0; ntd < 8; ntd++) {
        int row = ntd * 16 + n16;
        s16x8 vf = *(const s16x8*)(VsB + row * 64 + ((kseg * 4 + quad) ^ (row & 7)) * 8);
        o[ntd] = __builtin_amdgcn_mfma_f32_16x16x32_bf16(pa[kseg], vf, o[ntd], 0, 0, 0);
      }
      o[8] = __builtin_amdgcn_mfma_f32_16x16x32_bf16(pa[kseg], ones, o[8], 0, 0, 0);
    }

    if (i == tripsA - 1) {
#pragma unroll
      for (int r = 0; r < 4; r++) {
        float lsum = __shfl(o[8][r], l & 48);
        float inv = 1.0f / lsum;
        int qrow = q0A + quad * 4 + r;
#pragma unroll
        for (int ntd = 0; ntd < 8; ntd++)
          Out[(size_t)qrow * HID + h * HD + ntd * 16 + n16] = (ushort_t)f2bf_bits(o[ntd][r] * inv);
      }
#pragma unroll
      for (int nt2 = 0; nt2 < 9; nt2++) o[nt2] = (f32x4){0.f, 0.f, 0.f, 0.f};
#pragma unroll
      for (int r = 0; r < 4; r++) mrun[r] = -1e30f;
    }
  }

#pragma unroll
  for (int r = 0; r < 4; r++) {
    float lsum = __shfl(o[8][r], l & 48);
    float inv = 1.0f / lsum;
    int qrow = q0B + quad * 4 + r;
#pragma unroll
    for (int ntd = 0; ntd < 8; ntd++)
      Out[(size_t)qrow * HID + h * HD + ntd * 16 + n16] = (ushort_t)f2bf_bits(o[ntd][r] * inv);
  }
}

extern "C" void kernel_launch(void* const* d_in, const int* in_sizes, int n_in,
                              void* d_out, int out_size, void* d_ws, size_t ws_size,
                              hipStream_t stream) {
  const float* hidden = (const float*)d_in[0];
  const float* w_qkv  = (const float*)d_in[1];
  const float* w_o    = (const float*)d_in[2];
  float* out = (float*)d_out;
  char* ws = (char*)d_ws;

  // ws layout (96 MB peak, sequential-stream aliasing):
  ushort_t* hidden_bf = (ushort_t*)ws;                   // [2048][4096] bf16, dead after gemm1
  ushort_t* Qb        = (ushort_t*)ws;                   // aliases hidden_bf
  ushort_t* wqkv_bf   = (ushort_t*)(ws + 16777216);      // [6144][4096] bf16, dead after gemm1
  ushort_t* wo_bf     = (ushort_t*)(ws + 16777216);      // aliases wqkv_bf (written after gemm1)
  ushort_t* qkv       = (ushort_t*)(ws + 67108864);      // [2048][6144] bf16, dead after rope+vt
  ushort_t* attn_out  = (ushort_t*)(ws + 67108864);      // aliases qkv
  ushort_t* Kb        = (ushort_t*)(ws + 92274688);      // [8][2048][128] bf16
  ushort_t* Vtb       = (ushort_t*)(ws + 96468992);      // [8][128][2048] bf16

  cvt_hw<<<dim3(16384), 256, 0, stream>>>(hidden, w_qkv, hidden_bf, wqkv_bf);
  // 256x256 tiles: 8x24 = 192 blocks (1/CU, 8-phase template regime)
  gemm8p<false><<<dim3(8, 24), 512, 0, stream>>>(hidden_bf, wqkv_bf, (void*)qkv, 2048, 6144, 4096);
  rope_vt_cvtwo<<<dim3(10752), 256, 0, stream>>>(qkv, Qb, Kb, Vtb, w_o, wo_bf);
  attn_kernel<<<dim3(16, 32), 256, 0, stream>>>(Qb, Kb, Vtb, attn_out);
  // 8x16 = 128 blocks
  gemm8p<true><<<dim3(8, 16), 512, 0, stream>>>(attn_out, wo_bf, (void*)out, 2048, 4096, 4096);
}

// Round 5
// 506.111 us; speedup vs baseline: 1.1382x; 1.1382x over previous
//
#include <hip/hip_runtime.h>
#include <cstdint>

#define S_LEN 2048
#define HID   4096
#define NHQ   32
#define NKV   8
#define HD    128
#define QKV_N 6144

typedef float  f32x4 __attribute__((ext_vector_type(4)));
typedef short  s16x8 __attribute__((ext_vector_type(8)));
typedef unsigned short ushort_t;

typedef __attribute__((address_space(3))) void       lds_void;
typedef const __attribute__((address_space(1))) void gbl_void;

__device__ __forceinline__ void gload_lds16(const void* g, void* l) {
  __builtin_amdgcn_global_load_lds((gbl_void*)g, (lds_void*)l, 16, 0, 0);
}

__device__ __forceinline__ short f2bf_bits(float f) {
  union { __bf16 b; short s; } u;
  u.b = (__bf16)f;
  return u.s;
}
__device__ __forceinline__ float bf2f(unsigned short u) {
  union { unsigned int i; float f; } x;
  x.i = ((unsigned int)u) << 16;
  return x.f;
}

__device__ __forceinline__ void cvt8(const float* src, ushort_t* dst, int j) {
  const f32x4* s = (const f32x4*)src;
  f32x4 a = s[j * 2], b = s[j * 2 + 1];
  s16x8 r;
  r[0] = f2bf_bits(a[0]); r[1] = f2bf_bits(a[1]); r[2] = f2bf_bits(a[2]); r[3] = f2bf_bits(a[3]);
  r[4] = f2bf_bits(b[0]); r[5] = f2bf_bits(b[1]); r[6] = f2bf_bits(b[2]); r[7] = f2bf_bits(b[3]);
  *((s16x8*)dst + j) = r;
}

// ---------------- fused cvt: hidden (1048576 vec8) + w_qkv (3145728 vec8) ----------------
__global__ __launch_bounds__(256)
void cvt_hw(const float* __restrict__ h, const float* __restrict__ wq,
            ushort_t* __restrict__ hb, ushort_t* __restrict__ wqb) {
  int i = blockIdx.x * 256 + threadIdx.x;
  if (i < 1048576) cvt8(h, hb, i);
  else             cvt8(wq, wqb, i - 1048576);
}

// ---------------- bf16 GEMM, C[M][N] = A[M][K] * B[N][K]^T (round-0 structure) ----------
// 128x128 tile, BK=32, global_load_lds width=16, double-buffered LDS:
// stage for iter i+1 issued right after barrier i -> the barrier's vmcnt(0)
// drain hits loads that are one full compute phase old. ~3 blocks/CU implicit
// wave-level overlap (m114) carries this to ~838 TF; 8-phase ports measured
// worse 3x (rounds 1-4) -> this is the session's GEMM structure.
__device__ __forceinline__ s16x8 frag_b16(const ushort_t* tile, int row, int quad) {
  return *(const s16x8*)(tile + row * 32 + quad * 8);
}

template <bool OUTF32>
__global__ __launch_bounds__(256)
void gemm_bt_bf16(const ushort_t* __restrict__ Ag, const ushort_t* __restrict__ Bg,
                  void* __restrict__ Cp, int M, int N, int K) {
  __shared__ __align__(16) ushort_t As[2][128 * 32];
  __shared__ __align__(16) ushort_t Bs[2][128 * 32];
  const int t = threadIdx.x;
  const int w = t >> 6, l = t & 63;
  const int n16 = l & 15, quad = l >> 4;
  const int m0 = blockIdx.x * 128, n0 = blockIdx.y * 128;
  const int wm = (w >> 1) * 64, wn = (w & 1) * 64;

  // staging address components (fixed per thread)
  const int sIdx0 = (w * 2 + 0) * 64 + l;
  const int sIdx1 = (w * 2 + 1) * 64 + l;
  const int aRow0 = sIdx0 >> 2, aCs0 = (sIdx0 & 3) * 8;
  const int aRow1 = sIdx1 >> 2, aCs1 = (sIdx1 & 3) * 8;
  const ushort_t* Arow0 = Ag + (size_t)(m0 + aRow0) * K + aCs0;
  const ushort_t* Arow1 = Ag + (size_t)(m0 + aRow1) * K + aCs1;
  const ushort_t* Brow0 = Bg + (size_t)(n0 + aRow0) * K + aCs0;
  const ushort_t* Brow1 = Bg + (size_t)(n0 + aRow1) * K + aCs1;

  f32x4 acc[4][4] = {};

  auto stage = [&](int k0, int buf) {
    gload_lds16(Arow0 + k0, (char*)&As[buf][0] + (w * 2 + 0) * 1024);
    gload_lds16(Arow1 + k0, (char*)&As[buf][0] + (w * 2 + 1) * 1024);
    gload_lds16(Brow0 + k0, (char*)&Bs[buf][0] + (w * 2 + 0) * 1024);
    gload_lds16(Brow1 + k0, (char*)&Bs[buf][0] + (w * 2 + 1) * 1024);
  };
  auto compute = [&](int buf) {
    s16x8 afr[4], bfr[4];
#pragma unroll
    for (int i = 0; i < 4; i++) afr[i] = frag_b16(&As[buf][0], wm + i * 16 + n16, quad);
#pragma unroll
    for (int j = 0; j < 4; j++) bfr[j] = frag_b16(&Bs[buf][0], wn + j * 16 + n16, quad);
#pragma unroll
    for (int i = 0; i < 4; i++)
#pragma unroll
      for (int j = 0; j < 4; j++)
        acc[i][j] = __builtin_amdgcn_mfma_f32_16x16x32_bf16(afr[i], bfr[j], acc[i][j], 0, 0, 0);
  };

  const int nIter = K >> 5;  // K/32, even for K=4096
  stage(0, 0);
  for (int it = 0; it < nIter; it += 2) {
    __syncthreads();                                   // buf0 ready (staged one compute ago)
    if (it + 1 < nIter) stage((it + 1) << 5, 1);       // prefetch buf1
    compute(0);
    __syncthreads();                                   // buf1 ready
    if (it + 2 < nIter) stage((it + 2) << 5, 0);       // prefetch buf0
    compute(1);
  }

#pragma unroll
  for (int i = 0; i < 4; i++)
#pragma unroll
    for (int j = 0; j < 4; j++)
#pragma unroll
      for (int r = 0; r < 4; r++) {
        int row = m0 + wm + i * 16 + quad * 4 + r;
        int col = n0 + wn + j * 16 + n16;
        float v = acc[i][j][r];
        if constexpr (OUTF32) ((float*)Cp)[(size_t)row * N + col] = v;
        else ((ushort_t*)Cp)[(size_t)row * N + col] = (ushort_t)f2bf_bits(v);
      }
}

// ---------------- fused mid-pipeline: RoPE scatter + V-transpose + cvt(w_o) ----------------
// blocks [0,2048): rope row s; [2048,2560): v_transpose; [2560,10752): w_o cvt.
__global__ __launch_bounds__(256)
void rope_vt_cvtwo(const ushort_t* __restrict__ qkv, ushort_t* __restrict__ Q,
                   ushort_t* __restrict__ Kc, ushort_t* __restrict__ Vt,
                   const float* __restrict__ wo, ushort_t* __restrict__ wob) {
  __shared__ __align__(16) ushort_t tile[64][72];
  const int b = blockIdx.x;
  const int t = threadIdx.x;
  if (b < 2048) {
    const int s = b;
    const float LN1E4_64 = 0.14391156831212787f;  // ln(10000)/64
    for (int item = t; item < (NHQ + NKV) * 64; item += 256) {
      int head = item >> 6, i = item & 63;
      float f = expf(-(float)i * LN1E4_64);
      float ang = (float)s * f;
      float sn, cs;
      sincosf(ang, &sn, &cs);
      if (head < NHQ) {
        const ushort_t* src = qkv + (size_t)s * QKV_N + head * HD;
        float x1 = bf2f(src[i]), x2 = bf2f(src[64 + i]);
        const float sc = 0.08838834764831845f;  // 1/sqrt(128)
        ushort_t* dst = Q + ((size_t)head * S_LEN + s) * HD;
        dst[i]      = (ushort_t)f2bf_bits((x1 * cs - x2 * sn) * sc);
        dst[64 + i] = (ushort_t)f2bf_bits((x1 * sn + x2 * cs) * sc);
      } else {
        int kv = head - NHQ;
        const ushort_t* src = qkv + (size_t)s * QKV_N + 4096 + kv * HD;
        float x1 = bf2f(src[i]), x2 = bf2f(src[64 + i]);
        ushort_t* dst = Kc + ((size_t)kv * S_LEN + s) * HD;
        dst[i]      = (ushort_t)f2bf_bits(x1 * cs - x2 * sn);
        dst[64 + i] = (ushort_t)f2bf_bits(x1 * sn + x2 * cs);
      }
    }
  } else if (b < 2560) {
    const int bb = b - 2048;
    const int s0 = (bb & 31) * 64;
    const int by = bb >> 5;
    const int kv = by >> 1;
    const int d0 = (by & 1) * 64;
    {
      int r = t >> 2, c = (t & 3) * 16;
      const ushort_t* src = qkv + (size_t)(s0 + r) * QKV_N + 5120 + kv * HD + d0 + c;
      *(s16x8*)&tile[r][c]     = *(const s16x8*)src;
      *(s16x8*)&tile[r][c + 8] = *(const s16x8*)(src + 8);
    }
    __syncthreads();
    {
      int d = t >> 2, sseg = (t & 3) * 16;
      ushort_t* dst = Vt + ((size_t)kv * HD + d0 + d) * S_LEN + s0 + sseg;
      s16x8 o1, o2;
#pragma unroll
      for (int i = 0; i < 8; i++) { o1[i] = tile[sseg + i][d]; o2[i] = tile[sseg + 8 + i][d]; }
      *(s16x8*)dst = o1;
      *(s16x8*)(dst + 8) = o2;
    }
  } else {
    int j = (b - 2560) * 256 + t;  // 2097152 vec8 of w_o
    cvt8(wo, wob, j);
  }
}

// ---------------- Flash attention (round-0 structure + T13 defer-max + T5 setprio) -----
__global__ __launch_bounds__(256)
void attn_kernel(const ushort_t* __restrict__ Q, const ushort_t* __restrict__ Kc,
                 const ushort_t* __restrict__ Vt, ushort_t* __restrict__ Out) {
  __shared__ __align__(16) ushort_t Ks[2][64 * 128];   // 32 KB
  __shared__ __align__(16) ushort_t Vs[2][128 * 64];   // 32 KB
  __shared__ __align__(16) ushort_t Pl[4][16 * 72];    // 9 KB
  const int bx = blockIdx.x;                            // 0..15
  const int h = blockIdx.y;
  const int t = threadIdx.x, w = t >> 6, l = t & 63;
  const int n16 = l & 15, quad = l >> 4;
  const int kv = h >> 2;
  const ushort_t* Qh = Q  + (size_t)h  * S_LEN * HD;
  const ushort_t* Kh = Kc + (size_t)kv * S_LEN * HD;
  const ushort_t* Vh = Vt + (size_t)kv * HD * S_LEN;

  const int qtA = bx, qtB = 31 - bx;
  const int q0A = qtA * 64 + w * 16, q0B = qtB * 64 + w * 16;
  const int tripsA = qtA + 1;
  const int TOTAL = 33;

  s16x8 qfA[4], qfB[4];
#pragma unroll
  for (int ks = 0; ks < 4; ks++) {
    qfA[ks] = *(const s16x8*)(Qh + (size_t)(q0A + n16) * HD + ks * 32 + quad * 8);
    qfB[ks] = *(const s16x8*)(Qh + (size_t)(q0B + n16) * HD + ks * 32 + quad * 8);
  }

  s16x8 ones;
  {
    short v = (n16 == 0) ? (short)0x3F80 : (short)0;
#pragma unroll
    for (int j = 0; j < 8; j++) ones[j] = v;
  }

  f32x4 o[9] = {};
  float mrun[4] = {-1e30f, -1e30f, -1e30f, -1e30f};

  ushort_t* P = Pl[w];

  auto stage = [&](int k0, int buf) {
#pragma unroll
    for (int c = 0; c < 4; c++) {
      int idx = (c * 4 + w) * 64 + l;
      int row = idx >> 4, sc = idx & 15;
      int dseg = sc ^ (row & 15);
      gload_lds16(Kh + (size_t)(k0 + row) * HD + dseg * 8,
                  (char*)&Ks[buf][0] + (c * 4 + w) * 1024);
    }
#pragma unroll
    for (int c = 0; c < 4; c++) {
      int idx = (c * 4 + w) * 64 + l;
      int row = idx >> 3, sc = idx & 7;
      int ks2 = sc ^ (row & 7);
      gload_lds16(Vh + (size_t)row * S_LEN + k0 + ks2 * 8,
                  (char*)&Vs[buf][0] + (c * 4 + w) * 1024);
    }
  };

  stage(0, 0);

  for (int i = 0; i < TOTAL; i++) {
    const bool isA = (i < tripsA);
    const int kt = isA ? i : i - tripsA;
    const int q0 = isA ? q0A : q0B;
    const int k0 = kt * 64;
    const int buf = i & 1;

    __syncthreads();

    if (i + 1 < TOTAL) {
      const bool nA = (i + 1 < tripsA);
      const int nkt = nA ? (i + 1) : (i + 1 - tripsA);
      stage(nkt * 64, buf ^ 1);
    }

    const ushort_t* KsB = &Ks[buf][0];
    const ushort_t* VsB = &Vs[buf][0];

    f32x4 sacc[4] = {};
    __builtin_amdgcn_s_setprio(1);
#pragma unroll
    for (int ks = 0; ks < 4; ks++) {
      s16x8 qf = isA ? qfA[ks] : qfB[ks];
#pragma unroll
      for (int nt = 0; nt < 4; nt++) {
        int row = nt * 16 + n16;
        s16x8 kf = *(const s16x8*)(KsB + row * 128 + ((ks * 4 + quad) ^ (row & 15)) * 8);
        sacc[nt] = __builtin_amdgcn_mfma_f32_16x16x32_bf16(qf, kf, sacc[nt], 0, 0, 0);
      }
    }
    __builtin_amdgcn_s_setprio(0);

    if (k0 + 63 > q0) {
#pragma unroll
      for (int nt = 0; nt < 4; nt++)
#pragma unroll
        for (int r = 0; r < 4; r++) {
          int qrow = q0 + quad * 4 + r;
          int key  = k0 + nt * 16 + n16;
          if (key > qrow) sacc[nt][r] = -1e30f;
        }
    }

    // ---- online softmax with defer-max (T13, THR=8) ----
    // tmx[r] = 16-lane tile max; rescale only if any row's max exceeds the
    // running max by >8. Skipped path keeps m_old; P = exp(s-m_old) <= e^8
    // (bf16-safe); o[8] row-sum uses the same m, so normalization is exact.
    float tmx[4];
    int need = 0;
#pragma unroll
    for (int r = 0; r < 4; r++) {
      float tm = fmaxf(fmaxf(sacc[0][r], sacc[1][r]), fmaxf(sacc[2][r], sacc[3][r]));
#pragma unroll
      for (int d = 1; d < 16; d <<= 1) tm = fmaxf(tm, __shfl_xor(tm, d));
      tmx[r] = tm;
      need |= (tm > mrun[r] + 8.0f) ? 1 : 0;
    }
    if (__any(need)) {
#pragma unroll
      for (int r = 0; r < 4; r++) {
        float nm = fmaxf(mrun[r], tmx[r]);
        float alpha = __expf(mrun[r] - nm);
        mrun[r] = nm;
#pragma unroll
        for (int nt2 = 0; nt2 < 9; nt2++) o[nt2][r] *= alpha;
      }
    }
#pragma unroll
    for (int r = 0; r < 4; r++)
#pragma unroll
      for (int nt = 0; nt < 4; nt++) sacc[nt][r] = __expf(sacc[nt][r] - mrun[r]);

#pragma unroll
    for (int nt = 0; nt < 4; nt++)
#pragma unroll
      for (int r = 0; r < 4; r++)
        P[(quad * 4 + r) * 72 + nt * 16 + n16] = (ushort_t)f2bf_bits(sacc[nt][r]);
    asm volatile("s_waitcnt lgkmcnt(0)" ::: "memory");
    s16x8 pa[2];
#pragma unroll
    for (int kseg = 0; kseg < 2; kseg++)
      pa[kseg] = *(const s16x8*)(P + n16 * 72 + kseg * 32 + quad * 8);

    __builtin_amdgcn_s_setprio(1);
#pragma unroll
    for (int kseg = 0; kseg < 2; kseg++) {
#pragma unroll
      for (int ntd = 0; ntd < 8; ntd++) {
        int row = ntd * 16 + n16;
        s16x8 vf = *(const s16x8*)(VsB + row * 64 + ((kseg * 4 + quad) ^ (row & 7)) * 8);
        o[ntd] = __builtin_amdgcn_mfma_f32_16x16x32_bf16(pa[kseg], vf, o[ntd], 0, 0, 0);
      }
      o[8] = __builtin_amdgcn_mfma_f32_16x16x32_bf16(pa[kseg], ones, o[8], 0, 0, 0);
    }
    __builtin_amdgcn_s_setprio(0);

    if (i == tripsA - 1) {
#pragma unroll
      for (int r = 0; r < 4; r++) {
        float lsum = __shfl(o[8][r], l & 48);
        float inv = 1.0f / lsum;
        int qrow = q0A + quad * 4 + r;
#pragma unroll
        for (int ntd = 0; ntd < 8; ntd++)
          Out[(size_t)qrow * HID + h * HD + ntd * 16 + n16] = (ushort_t)f2bf_bits(o[ntd][r] * inv);
      }
#pragma unroll
      for (int nt2 = 0; nt2 < 9; nt2++) o[nt2] = (f32x4){0.f, 0.f, 0.f, 0.f};
#pragma unroll
      for (int r = 0; r < 4; r++) mrun[r] = -1e30f;
    }
  }

#pragma unroll
  for (int r = 0; r < 4; r++) {
    float lsum = __shfl(o[8][r], l & 48);
    float inv = 1.0f / lsum;
    int qrow = q0B + quad * 4 + r;
#pragma unroll
    for (int ntd = 0; ntd < 8; ntd++)
      Out[(size_t)qrow * HID + h * HD + ntd * 16 + n16] = (ushort_t)f2bf_bits(o[ntd][r] * inv);
  }
}

extern "C" void kernel_launch(void* const* d_in, const int* in_sizes, int n_in,
                              void* d_out, int out_size, void* d_ws, size_t ws_size,
                              hipStream_t stream) {
  const float* hidden = (const float*)d_in[0];
  const float* w_qkv  = (const float*)d_in[1];
  const float* w_o    = (const float*)d_in[2];
  float* out = (float*)d_out;
  char* ws = (char*)d_ws;

  // ws layout (96 MB peak, sequential-stream aliasing):
  ushort_t* hidden_bf = (ushort_t*)ws;                   // [2048][4096] bf16, dead after gemm1
  ushort_t* Qb        = (ushort_t*)ws;                   // aliases hidden_bf
  ushort_t* wqkv_bf   = (ushort_t*)(ws + 16777216);      // [6144][4096] bf16, dead after gemm1
  ushort_t* wo_bf     = (ushort_t*)(ws + 16777216);      // aliases wqkv_bf (written after gemm1)
  ushort_t* qkv       = (ushort_t*)(ws + 67108864);      // [2048][6144] bf16, dead after rope+vt
  ushort_t* attn_out  = (ushort_t*)(ws + 67108864);      // aliases qkv
  ushort_t* Kb        = (ushort_t*)(ws + 92274688);      // [8][2048][128] bf16
  ushort_t* Vtb       = (ushort_t*)(ws + 96468992);      // [8][128][2048] bf16

  cvt_hw<<<dim3(16384), 256, 0, stream>>>(hidden, w_qkv, hidden_bf, wqkv_bf);
  gemm_bt_bf16<false><<<dim3(16, 48), 256, 0, stream>>>(hidden_bf, wqkv_bf, (void*)qkv, 2048, 6144, 4096);
  rope_vt_cvtwo<<<dim3(10752), 256, 0, stream>>>(qkv, Qb, Kb, Vtb, w_o, wo_bf);
  attn_kernel<<<dim3(16, 32), 256, 0, stream>>>(Qb, Kb, Vtb, attn_out);
  gemm_bt_bf16<true><<<dim3(16, 32), 256, 0, stream>>>(attn_out, wo_bf, (void*)out, 2048, 4096, 4096);
}

// Round 6
// 502.587 us; speedup vs baseline: 1.1462x; 1.0070x over previous
//
#include <hip/hip_runtime.h>
#include <cstdint>

#define S_LEN 2048
#define HID   4096
#define NHQ   32
#define NKV   8
#define HD    128
#define QKV_N 6144

typedef float  f32x4 __attribute__((ext_vector_type(4)));
typedef short  s16x8 __attribute__((ext_vector_type(8)));
typedef unsigned short ushort_t;

typedef __attribute__((address_space(3))) void       lds_void;
typedef const __attribute__((address_space(1))) void gbl_void;

__device__ __forceinline__ void gload_lds16(const void* g, void* l) {
  __builtin_amdgcn_global_load_lds((gbl_void*)g, (lds_void*)l, 16, 0, 0);
}

__device__ __forceinline__ short f2bf_bits(float f) {
  union { __bf16 b; short s; } u;
  u.b = (__bf16)f;
  return u.s;
}
__device__ __forceinline__ float bf2f(unsigned short u) {
  union { unsigned int i; float f; } x;
  x.i = ((unsigned int)u) << 16;
  return x.f;
}

__device__ __forceinline__ void cvt8(const float* src, ushort_t* dst, int j) {
  const f32x4* s = (const f32x4*)src;
  f32x4 a = s[j * 2], b = s[j * 2 + 1];
  s16x8 r;
  r[0] = f2bf_bits(a[0]); r[1] = f2bf_bits(a[1]); r[2] = f2bf_bits(a[2]); r[3] = f2bf_bits(a[3]);
  r[4] = f2bf_bits(b[0]); r[5] = f2bf_bits(b[1]); r[6] = f2bf_bits(b[2]); r[7] = f2bf_bits(b[3]);
  *((s16x8*)dst + j) = r;
}

// ---------------- fused cvt: hidden (1048576 vec8) + w_qkv (3145728 vec8) ----------------
__global__ __launch_bounds__(256)
void cvt_hw(const float* __restrict__ h, const float* __restrict__ wq,
            ushort_t* __restrict__ hb, ushort_t* __restrict__ wqb) {
  int i = blockIdx.x * 256 + threadIdx.x;
  if (i < 1048576) cvt8(h, hb, i);
  else             cvt8(wq, wqb, i - 1048576);
}

// ---------------- bf16 GEMM, C[M][N] = A[M][K] * B[N][K]^T (round-0 structure) ----------
// 128x128 tile, BK=32, global_load_lds width=16, double-buffered LDS. ~3 blocks/CU
// implicit wave-level overlap carries this to ~838 TF; 8-phase ports measured worse
// 3x (rounds 1-4) -> frozen as the session's GEMM structure.
__device__ __forceinline__ s16x8 frag_b16(const ushort_t* tile, int row, int quad) {
  return *(const s16x8*)(tile + row * 32 + quad * 8);
}

template <bool OUTF32>
__global__ __launch_bounds__(256)
void gemm_bt_bf16(const ushort_t* __restrict__ Ag, const ushort_t* __restrict__ Bg,
                  void* __restrict__ Cp, int M, int N, int K) {
  __shared__ __align__(16) ushort_t As[2][128 * 32];
  __shared__ __align__(16) ushort_t Bs[2][128 * 32];
  const int t = threadIdx.x;
  const int w = t >> 6, l = t & 63;
  const int n16 = l & 15, quad = l >> 4;
  const int m0 = blockIdx.x * 128, n0 = blockIdx.y * 128;
  const int wm = (w >> 1) * 64, wn = (w & 1) * 64;

  const int sIdx0 = (w * 2 + 0) * 64 + l;
  const int sIdx1 = (w * 2 + 1) * 64 + l;
  const int aRow0 = sIdx0 >> 2, aCs0 = (sIdx0 & 3) * 8;
  const int aRow1 = sIdx1 >> 2, aCs1 = (sIdx1 & 3) * 8;
  const ushort_t* Arow0 = Ag + (size_t)(m0 + aRow0) * K + aCs0;
  const ushort_t* Arow1 = Ag + (size_t)(m0 + aRow1) * K + aCs1;
  const ushort_t* Brow0 = Bg + (size_t)(n0 + aRow0) * K + aCs0;
  const ushort_t* Brow1 = Bg + (size_t)(n0 + aRow1) * K + aCs1;

  f32x4 acc[4][4] = {};

  auto stage = [&](int k0, int buf) {
    gload_lds16(Arow0 + k0, (char*)&As[buf][0] + (w * 2 + 0) * 1024);
    gload_lds16(Arow1 + k0, (char*)&As[buf][0] + (w * 2 + 1) * 1024);
    gload_lds16(Brow0 + k0, (char*)&Bs[buf][0] + (w * 2 + 0) * 1024);
    gload_lds16(Brow1 + k0, (char*)&Bs[buf][0] + (w * 2 + 1) * 1024);
  };
  auto compute = [&](int buf) {
    s16x8 afr[4], bfr[4];
#pragma unroll
    for (int i = 0; i < 4; i++) afr[i] = frag_b16(&As[buf][0], wm + i * 16 + n16, quad);
#pragma unroll
    for (int j = 0; j < 4; j++) bfr[j] = frag_b16(&Bs[buf][0], wn + j * 16 + n16, quad);
#pragma unroll
    for (int i = 0; i < 4; i++)
#pragma unroll
      for (int j = 0; j < 4; j++)
        acc[i][j] = __builtin_amdgcn_mfma_f32_16x16x32_bf16(afr[i], bfr[j], acc[i][j], 0, 0, 0);
  };

  const int nIter = K >> 5;
  stage(0, 0);
  for (int it = 0; it < nIter; it += 2) {
    __syncthreads();
    if (it + 1 < nIter) stage((it + 1) << 5, 1);
    compute(0);
    __syncthreads();
    if (it + 2 < nIter) stage((it + 2) << 5, 0);
    compute(1);
  }

#pragma unroll
  for (int i = 0; i < 4; i++)
#pragma unroll
    for (int j = 0; j < 4; j++)
#pragma unroll
      for (int r = 0; r < 4; r++) {
        int row = m0 + wm + i * 16 + quad * 4 + r;
        int col = n0 + wn + j * 16 + n16;
        float v = acc[i][j][r];
        if constexpr (OUTF32) ((float*)Cp)[(size_t)row * N + col] = v;
        else ((ushort_t*)Cp)[(size_t)row * N + col] = (ushort_t)f2bf_bits(v);
      }
}

// ---------------- fused mid-pipeline: RoPE scatter + V-transpose + cvt(w_o) ----------------
__global__ __launch_bounds__(256)
void rope_vt_cvtwo(const ushort_t* __restrict__ qkv, ushort_t* __restrict__ Q,
                   ushort_t* __restrict__ Kc, ushort_t* __restrict__ Vt,
                   const float* __restrict__ wo, ushort_t* __restrict__ wob) {
  __shared__ __align__(16) ushort_t tile[64][72];
  const int b = blockIdx.x;
  const int t = threadIdx.x;
  if (b < 2048) {
    const int s = b;
    const float LN1E4_64 = 0.14391156831212787f;  // ln(10000)/64
    for (int item = t; item < (NHQ + NKV) * 64; item += 256) {
      int head = item >> 6, i = item & 63;
      float f = expf(-(float)i * LN1E4_64);
      float ang = (float)s * f;
      float sn, cs;
      sincosf(ang, &sn, &cs);
      if (head < NHQ) {
        const ushort_t* src = qkv + (size_t)s * QKV_N + head * HD;
        float x1 = bf2f(src[i]), x2 = bf2f(src[64 + i]);
        const float sc = 0.08838834764831845f;  // 1/sqrt(128)
        ushort_t* dst = Q + ((size_t)head * S_LEN + s) * HD;
        dst[i]      = (ushort_t)f2bf_bits((x1 * cs - x2 * sn) * sc);
        dst[64 + i] = (ushort_t)f2bf_bits((x1 * sn + x2 * cs) * sc);
      } else {
        int kv = head - NHQ;
        const ushort_t* src = qkv + (size_t)s * QKV_N + 4096 + kv * HD;
        float x1 = bf2f(src[i]), x2 = bf2f(src[64 + i]);
        ushort_t* dst = Kc + ((size_t)kv * S_LEN + s) * HD;
        dst[i]      = (ushort_t)f2bf_bits(x1 * cs - x2 * sn);
        dst[64 + i] = (ushort_t)f2bf_bits(x1 * sn + x2 * cs);
      }
    }
  } else if (b < 2560) {
    const int bb = b - 2048;
    const int s0 = (bb & 31) * 64;
    const int by = bb >> 5;
    const int kv = by >> 1;
    const int d0 = (by & 1) * 64;
    {
      int r = t >> 2, c = (t & 3) * 16;
      const ushort_t* src = qkv + (size_t)(s0 + r) * QKV_N + 5120 + kv * HD + d0 + c;
      *(s16x8*)&tile[r][c]     = *(const s16x8*)src;
      *(s16x8*)&tile[r][c + 8] = *(const s16x8*)(src + 8);
    }
    __syncthreads();
    {
      int d = t >> 2, sseg = (t & 3) * 16;
      ushort_t* dst = Vt + ((size_t)kv * HD + d0 + d) * S_LEN + s0 + sseg;
      s16x8 o1, o2;
#pragma unroll
      for (int i = 0; i < 8; i++) { o1[i] = tile[sseg + i][d]; o2[i] = tile[sseg + 8 + i][d]; }
      *(s16x8*)dst = o1;
      *(s16x8*)(dst + 8) = o2;
    }
  } else {
    int j = (b - 2560) * 256 + t;  // 2097152 vec8 of w_o
    cvt8(wo, wob, j);
  }
}

// ---------------- Flash attention: KVBLK=32, 4 blocks/CU (16 waves/CU) -----------------
// Restructure rationale (round-5 post-mortem): the per-trip serial chain was limited by
// 8 waves/CU (LDS 73.75KB -> 2 blocks/CU). KVBLK=32 cuts LDS to 36KB -> 4 blocks/CU,
// 16 waves/CU. One q-tile per block (1024 blocks), trips = 2qt+2; grid decode spreads
// qt as {j, 31-j, 8+j, 23-j} so co-resident blocks' work sums ~constant per CU.
// Steady-state softmax avoids the shuffle-reduce entirely (compare-based defer check);
// full reduce only on the rare rescale path (T13, THR=8).
__global__ __launch_bounds__(256)
void attn_kernel(const ushort_t* __restrict__ Q, const ushort_t* __restrict__ Kc,
                 const ushort_t* __restrict__ Vt, ushort_t* __restrict__ Out) {
  __shared__ __align__(16) ushort_t Ks[2][32 * 128];   // 8 KB x2
  __shared__ __align__(16) ushort_t Vs[2][128 * 32];   // 8 KB x2
  __shared__ __align__(16) ushort_t Pl[4][16 * 32];    // 1 KB per wave
  const int bidx = blockIdx.x;
  const int g = bidx >> 8, rr = bidx & 255;
  const int h = rr >> 3, j = rr & 7;
  const int qt = (g == 0) ? j : (g == 1) ? (31 - j) : (g == 2) ? (8 + j) : (23 - j);
  const int t = threadIdx.x, w = t >> 6, l = t & 63;
  const int n16 = l & 15, quad = l >> 4;
  const int kv = h >> 2;
  const ushort_t* Qh = Q  + (size_t)h  * S_LEN * HD;
  const ushort_t* Kh = Kc + (size_t)kv * S_LEN * HD;
  const ushort_t* Vh = Vt + (size_t)kv * HD * S_LEN;
  const int q0 = qt * 64 + w * 16;       // this wave's 16 q-rows
  const int NT = 2 * qt + 2;             // kv tiles of 32

  s16x8 qf[4];
#pragma unroll
  for (int ks = 0; ks < 4; ks++)
    qf[ks] = *(const s16x8*)(Qh + (size_t)(q0 + n16) * HD + ks * 32 + quad * 8);

  s16x8 ones;
  {
    short v = (n16 == 0) ? (short)0x3F80 : (short)0;
#pragma unroll
    for (int jj = 0; jj < 8; jj++) ones[jj] = v;
  }

  f32x4 o[9] = {};
  float mrun[4] = {-1e30f, -1e30f, -1e30f, -1e30f};
  ushort_t* P = Pl[w];

  // Staging: K tile 32x128 (8KB) + V tile 128x32 (8KB); 2+2 gload_lds per thread.
  // Byte-seg swizzles match the read-side XORs (dense-1KB reads per ds_read_b128).
  auto stage = [&](int k0, int buf) {
#pragma unroll
    for (int c = 0; c < 2; c++) {
      int idx = c * 256 + t;
      int row = idx >> 4, sc = idx & 15;
      int dseg = sc ^ (row & 15);
      gload_lds16(Kh + (size_t)(k0 + row) * HD + dseg * 8,
                  (char*)&Ks[buf][0] + idx * 16);
    }
#pragma unroll
    for (int c = 0; c < 2; c++) {
      int idx = c * 256 + t;
      int row = idx >> 2, sc = idx & 3;
      int ks2 = sc ^ (row & 3);
      gload_lds16(Vh + (size_t)row * S_LEN + k0 + ks2 * 8,
                  (char*)&Vs[buf][0] + idx * 16);
    }
  };

  stage(0, 0);

  for (int i = 0; i < NT; i++) {
    const int k0 = i * 32;
    const int buf = i & 1;

    __syncthreads();
    if (i + 1 < NT) stage((i + 1) * 32, buf ^ 1);

    if (k0 <= q0 + 15) {  // wave has unmasked keys this trip (no barriers inside)
      const ushort_t* KsB = &Ks[buf][0];
      const ushort_t* VsB = &Vs[buf][0];

      f32x4 sacc[2] = {};
      __builtin_amdgcn_s_setprio(1);
#pragma unroll
      for (int ks = 0; ks < 4; ks++)
#pragma unroll
        for (int nt = 0; nt < 2; nt++) {
          int row = nt * 16 + n16;
          s16x8 kf = *(const s16x8*)(KsB + row * 128 + ((ks * 4 + quad) ^ (row & 15)) * 8);
          sacc[nt] = __builtin_amdgcn_mfma_f32_16x16x32_bf16(qf[ks], kf, sacc[nt], 0, 0, 0);
        }
      __builtin_amdgcn_s_setprio(0);

      if (k0 + 31 > q0) {
#pragma unroll
        for (int nt = 0; nt < 2; nt++)
#pragma unroll
          for (int r = 0; r < 4; r++) {
            int qrow = q0 + quad * 4 + r;
            int key  = k0 + nt * 16 + n16;
            if (key > qrow) sacc[nt][r] = -1e30f;
          }
      }

      // defer-max: cheap compare-based check (no shuffles in the common path)
      int need = 0;
#pragma unroll
      for (int r = 0; r < 4; r++)
#pragma unroll
        for (int nt = 0; nt < 2; nt++)
          need |= (sacc[nt][r] > mrun[r] + 8.0f) ? 1 : 0;
      if (__any(need)) {
#pragma unroll
        for (int r = 0; r < 4; r++) {
          float tm = fmaxf(sacc[0][r], sacc[1][r]);
#pragma unroll
          for (int d = 1; d < 16; d <<= 1) tm = fmaxf(tm, __shfl_xor(tm, d));
          float nm = fmaxf(mrun[r], tm);
          float alpha = __expf(mrun[r] - nm);
          mrun[r] = nm;
#pragma unroll
          for (int nt2 = 0; nt2 < 9; nt2++) o[nt2][r] *= alpha;
        }
      }
#pragma unroll
      for (int r = 0; r < 4; r++)
#pragma unroll
        for (int nt = 0; nt < 2; nt++)
          sacc[nt][r] = __expf(sacc[nt][r] - mrun[r]);

#pragma unroll
      for (int nt = 0; nt < 2; nt++)
#pragma unroll
        for (int r = 0; r < 4; r++)
          P[(quad * 4 + r) * 32 + nt * 16 + n16] = (ushort_t)f2bf_bits(sacc[nt][r]);
      asm volatile("s_waitcnt lgkmcnt(0)" ::: "memory");
      s16x8 pa = *(const s16x8*)(P + n16 * 32 + quad * 8);

      __builtin_amdgcn_s_setprio(1);
#pragma unroll
      for (int ntd = 0; ntd < 8; ntd++) {
        int row = ntd * 16 + n16;
        s16x8 vf = *(const s16x8*)(VsB + row * 32 + ((quad ^ (row & 3))) * 8);
        o[ntd] = __builtin_amdgcn_mfma_f32_16x16x32_bf16(pa, vf, o[ntd], 0, 0, 0);
      }
      o[8] = __builtin_amdgcn_mfma_f32_16x16x32_bf16(pa, ones, o[8], 0, 0, 0);
      __builtin_amdgcn_s_setprio(0);
    }
  }

#pragma unroll
  for (int r = 0; r < 4; r++) {
    float lsum = __shfl(o[8][r], l & 48);
    float inv = 1.0f / lsum;
    int qrow = q0 + quad * 4 + r;
#pragma unroll
    for (int ntd = 0; ntd < 8; ntd++)
      Out[(size_t)qrow * HID + h * HD + ntd * 16 + n16] = (ushort_t)f2bf_bits(o[ntd][r] * inv);
  }
}

extern "C" void kernel_launch(void* const* d_in, const int* in_sizes, int n_in,
                              void* d_out, int out_size, void* d_ws, size_t ws_size,
                              hipStream_t stream) {
  const float* hidden = (const float*)d_in[0];
  const float* w_qkv  = (const float*)d_in[1];
  const float* w_o    = (const float*)d_in[2];
  float* out = (float*)d_out;
  char* ws = (char*)d_ws;

  // ws layout (96 MB peak, sequential-stream aliasing):
  ushort_t* hidden_bf = (ushort_t*)ws;                   // [2048][4096] bf16, dead after gemm1
  ushort_t* Qb        = (ushort_t*)ws;                   // aliases hidden_bf
  ushort_t* wqkv_bf   = (ushort_t*)(ws + 16777216);      // [6144][4096] bf16, dead after gemm1
  ushort_t* wo_bf     = (ushort_t*)(ws + 16777216);      // aliases wqkv_bf (written after gemm1)
  ushort_t* qkv       = (ushort_t*)(ws + 67108864);      // [2048][6144] bf16, dead after rope+vt
  ushort_t* attn_out  = (ushort_t*)(ws + 67108864);      // aliases qkv
  ushort_t* Kb        = (ushort_t*)(ws + 92274688);      // [8][2048][128] bf16
  ushort_t* Vtb       = (ushort_t*)(ws + 96468992);      // [8][128][2048] bf16

  cvt_hw<<<dim3(16384), 256, 0, stream>>>(hidden, w_qkv, hidden_bf, wqkv_bf);
  gemm_bt_bf16<false><<<dim3(16, 48), 256, 0, stream>>>(hidden_bf, wqkv_bf, (void*)qkv, 2048, 6144, 4096);
  rope_vt_cvtwo<<<dim3(10752), 256, 0, stream>>>(qkv, Qb, Kb, Vtb, w_o, wo_bf);
  attn_kernel<<<dim3(1024), 256, 0, stream>>>(Qb, Kb, Vtb, attn_out);
  gemm_bt_bf16<true><<<dim3(16, 32), 256, 0, stream>>>(attn_out, wo_bf, (void*)out, 2048, 4096, 4096);
}